// Round 4
// baseline (151.566 us; speedup 1.0000x reference)
//
#include <hip/hip_runtime.h>
#include <math.h>

#define DD 160
#define HH 160
#define WW 160
#define NB 2
#define SLICE (HH * WW)        // 25600
#define NV 51200               // NB*160*160 vectors per reduction type
#define NVTOT (4 * NV)         // gxH, gzH, gyD, gzD
#define NC 5                   // chunks per reduced axis
#define RPC 32                 // rows (slices) per chunk
#define NIT 4                  // iterations: RPC / 8 groups
#define NTHR 320               // 8 groups x 40 float4-lanes

static constexpr float EPS = 1e-12f;
static constexpr float SCALE = -1.0f / 960.0f;  // -(six cos sums)/(160*2*3)

#define ELEM(v, j) ((j) == 0 ? (v).x : ((j) == 1 ? (v).y : ((j) == 2 ? (v).z : (v).w)))

__global__ void zero_kernel(float* out) {
  if (threadIdx.x == 0) out[0] = 0.0f;
}

// ---------------------------------------------------------------------------
// Fused main pass. Even blocks: role A (h-major): alongW cosines (gx,gy) +
// alongH partials (gx,gz). Odd blocks: role B (d-major): alongD partials
// (gy,gz). Main loops are sync-free; all block reductions deferred to tail.
// ---------------------------------------------------------------------------
__global__ __launch_bounds__(NTHR) void mainAB(const float* __restrict__ f,
                                               const float* __restrict__ t,
                                               float* __restrict__ P,
                                               float* __restrict__ out) {
  __shared__ float sd[8960];       // A: [32 rows][40 l][7]; tail/B: [8 g][40 l][25]
  __shared__ float red[32][6];
  __shared__ float cpad[32];
  const int tid = threadIdx.x;
  const int l = tid % 40;
  const int g = tid / 40;
  const int w = 4 * l;
  const int wn = (w + 4 < WW) ? (w + 4) : (WW - 1);  // clamp -> gz[3]=0 at w=159
  const int blk = blockIdx.x;

  if ((blk & 1) == 0) {
    // ---------------- role A ----------------
    const int id = blk >> 1;
    const int hc = id % NC;
    const int bd = id / NC;
    const int d = bd % DD;
    const size_t base = (size_t)bd * SLICE;
    const float* fp = f + base;
    const float* tp = t + base;
    const int dstep = (d < DD - 1) ? SLICE : 0;      // clamp -> gx = 0
    float ah[24];
#pragma unroll
    for (int c = 0; c < 24; ++c) ah[c] = 0.0f;

#pragma unroll
    for (int it = 0; it < NIT; ++it) {
      const int rl = it * 8 + g;                     // local row 0..31
      const int h = hc * RPC + rl;
      const int hstep = (h < HH - 1) ? WW : 0;       // clamp -> gy = 0
      const float* rf = fp + h * WW;
      const float* rt = tp + h * WW;
      const float4 F0 = *(const float4*)(rf + w);
      const float4 T0 = *(const float4*)(rt + w);
      const float4 FD = *(const float4*)(rf + dstep + w);
      const float4 TD = *(const float4*)(rt + dstep + w);
      const float4 FH = *(const float4*)(rf + hstep + w);
      const float4 TH = *(const float4*)(rt + hstep + w);
      const float fz = rf[wn], tz = rt[wn];
      float xd = 0, xf = 0, xt = 0, yd = 0, yf = 0, yt = 0;
#pragma unroll
      for (int j = 0; j < 4; ++j) {
        const float f0 = ELEM(F0, j), t0 = ELEM(T0, j);
        const float gxf = ELEM(FD, j) - f0, gxt = ELEM(TD, j) - t0;
        const float gyf = ELEM(FH, j) - f0, gyt = ELEM(TH, j) - t0;
        const float fnx = (j < 3) ? ELEM(F0, j + 1) : fz;
        const float tnx = (j < 3) ? ELEM(T0, j + 1) : tz;
        const float gzf = fnx - f0, gzt = tnx - t0;
        xd += gxf * gxt; xf += gxf * gxf; xt += gxt * gxt;
        yd += gyf * gyt; yf += gyf * gyf; yt += gyt * gyt;
        ah[j * 6 + 0] += gxf * gxt; ah[j * 6 + 1] += gxf * gxf; ah[j * 6 + 2] += gxt * gxt;
        ah[j * 6 + 3] += gzf * gzt; ah[j * 6 + 4] += gzf * gzf; ah[j * 6 + 5] += gzt * gzt;
      }
      // each (row,lane) slot written exactly once -> no sync needed here
      float* s = &sd[(rl * 40 + l) * 7];
      s[0] = xd; s[1] = xf; s[2] = xt; s[3] = yd; s[4] = yf; s[5] = yt;
    }
    __syncthreads();
    // alongW reduce over 40 lanes: 192 tasks (32 rows x 6 sums)
    if (tid < 192) {
      const int row = tid / 6, c = tid % 6;
      float s = 0.0f;
#pragma unroll 8
      for (int ll = 0; ll < 40; ++ll) s += sd[(row * 40 + ll) * 7 + c];
      red[row][c] = s;
    }
    __syncthreads();
    if (tid < 32) {
      const float cx = red[tid][0] / (fmaxf(sqrtf(red[tid][1]), EPS) * fmaxf(sqrtf(red[tid][2]), EPS));
      const float cy = red[tid][3] / (fmaxf(sqrtf(red[tid][4]), EPS) * fmaxf(sqrtf(red[tid][5]), EPS));
      cpad[tid] = cx + cy;
    }
    // alongH: stash per-thread partials (sd reads all completed before sync2)
    float* s3 = &sd[(g * 40 + l) * 25];
#pragma unroll
    for (int c = 0; c < 24; ++c) s3[c] = ah[c];
    __syncthreads();
    if (tid == 0) {
      float s = 0.0f;
#pragma unroll
      for (int i = 0; i < 32; ++i) s += cpad[i];
      atomicAdd(out, s * SCALE);
    }
    for (int task = tid; task < 960; task += NTHR) {
      const int ll = task / 24, c = task % 24;
      float s = 0.0f;
#pragma unroll
      for (int gg = 0; gg < 8; ++gg) s += sd[(gg * 40 + ll) * 25 + c];
      const int j = c / 6, cc = c % 6;
      const int wi = 4 * ll + j;
      const size_t vec = (cc < 3) ? (size_t)(bd * 160 + wi) : (size_t)(NV + bd * 160 + wi);
      P[((size_t)hc * NVTOT + vec) * 3 + (cc % 3)] = s;
    }
  } else {
    // ---------------- role B ----------------
    const int id = blk >> 1;
    const int dc = id % NC;
    const int bh = id / NC;
    const int b = bh / HH;
    const int h = bh % HH;
    const size_t base = (size_t)b * DD * SLICE + (size_t)h * WW;
    const float* fp = f + base;
    const float* tp = t + base;
    const int hstep = (h < HH - 1) ? WW : 0;
    float ad[24];
#pragma unroll
    for (int c = 0; c < 24; ++c) ad[c] = 0.0f;

#pragma unroll
    for (int it = 0; it < NIT; ++it) {
      const int dloc = dc * RPC + it * 8 + g;
      const float* rf = fp + (size_t)dloc * SLICE;
      const float* rt = tp + (size_t)dloc * SLICE;
      const float4 F0 = *(const float4*)(rf + w);
      const float4 T0 = *(const float4*)(rt + w);
      const float4 FH = *(const float4*)(rf + hstep + w);
      const float4 TH = *(const float4*)(rt + hstep + w);
      const float fz = rf[wn], tz = rt[wn];
#pragma unroll
      for (int j = 0; j < 4; ++j) {
        const float f0 = ELEM(F0, j), t0 = ELEM(T0, j);
        const float gyf = ELEM(FH, j) - f0, gyt = ELEM(TH, j) - t0;
        const float fnx = (j < 3) ? ELEM(F0, j + 1) : fz;
        const float tnx = (j < 3) ? ELEM(T0, j + 1) : tz;
        const float gzf = fnx - f0, gzt = tnx - t0;
        ad[j * 6 + 0] += gyf * gyt; ad[j * 6 + 1] += gyf * gyf; ad[j * 6 + 2] += gyt * gyt;
        ad[j * 6 + 3] += gzf * gzt; ad[j * 6 + 4] += gzf * gzf; ad[j * 6 + 5] += gzt * gzt;
      }
    }
    float* s3 = &sd[(g * 40 + l) * 25];
#pragma unroll
    for (int c = 0; c < 24; ++c) s3[c] = ad[c];
    __syncthreads();
    for (int task = tid; task < 960; task += NTHR) {
      const int ll = task / 24, c = task % 24;
      float s = 0.0f;
#pragma unroll
      for (int gg = 0; gg < 8; ++gg) s += sd[(gg * 40 + ll) * 25 + c];
      const int j = c / 6, cc = c % 6;
      const int wi = 4 * ll + j;
      const size_t vec = (cc < 3) ? (size_t)(2 * NV + bh * 160 + wi) : (size_t)(3 * NV + bh * 160 + wi);
      P[((size_t)dc * NVTOT + vec) * 3 + (cc % 3)] = s;
    }
  }
}

// ---------------------------------------------------------------------------
// Combine chunk partials -> cosines -> loss.
// ---------------------------------------------------------------------------
__global__ __launch_bounds__(256) void finalize_kernel(const float* __restrict__ P,
                                                       float* __restrict__ out) {
  const int v = blockIdx.x * 256 + threadIdx.x;
  float c = 0.0f;
  if (v < NVTOT) {
    float dot = 0.0f, ff = 0.0f, tt = 0.0f;
#pragma unroll
    for (int ch = 0; ch < NC; ++ch) {
      const size_t o = ((size_t)ch * NVTOT + v) * 3;
      dot += P[o]; ff += P[o + 1]; tt += P[o + 2];
    }
    c = dot / (fmaxf(sqrtf(ff), EPS) * fmaxf(sqrtf(tt), EPS));
  }
#pragma unroll
  for (int m = 32; m >= 1; m >>= 1) c += __shfl_xor(c, m);
  __shared__ float part[4];
  if ((threadIdx.x & 63) == 0) part[threadIdx.x >> 6] = c;
  __syncthreads();
  if (threadIdx.x == 0) atomicAdd(out, (part[0] + part[1] + part[2] + part[3]) * SCALE);
}

extern "C" void kernel_launch(void* const* d_in, const int* in_sizes, int n_in,
                              void* d_out, int out_size, void* d_ws, size_t ws_size,
                              hipStream_t stream) {
  const float* fk = (const float*)d_in[0];
  const float* tr = (const float*)d_in[1];
  float* out = (float*)d_out;
  float* P = (float*)d_ws;   // NC*NVTOT*3 floats = 12.3 MB (ws observed ~268 MB)

  hipLaunchKernelGGL(zero_kernel, dim3(1), dim3(64), 0, stream, out);
  hipLaunchKernelGGL(mainAB, dim3(2 * NB * DD * NC), dim3(NTHR), 0, stream, fk, tr, P, out);
  hipLaunchKernelGGL(finalize_kernel, dim3((NVTOT + 255) / 256), dim3(256), 0, stream, P, out);
}

// Round 5
// 148.519 us; speedup vs baseline: 1.0205x; 1.0205x over previous
//
#include <hip/hip_runtime.h>
#include <math.h>

#define DD 160
#define HH 160
#define WW 160
#define NB 2
#define SLICE (HH * WW)        // 25600
#define NV 51200               // NB*160*160 vectors per reduction type
#define NVTOT (4 * NV)         // gxH, gzH, gyD, gzD
#define NC 5                   // chunks per reduced axis
#define RPC 32                 // rows (slices) per chunk
#define RPW 8                  // consecutive rows per wave
#define NTHR 256               // 4 waves
#define NWAVE 4

static constexpr float EPS = 1e-12f;
static constexpr float SCALE = -1.0f / 960.0f;  // -(six cos sums)/(160*2*3)

#define ELEM(v, j) ((j) == 0 ? (v).x : ((j) == 1 ? (v).y : ((j) == 2 ? (v).z : (v).w)))

__global__ void zero_kernel(float* out) {
  if (threadIdx.x == 0) out[0] = 0.0f;
}

// ---------------------------------------------------------------------------
// Fused main pass, wave-aligned. Even blocks: role A (h-walk): alongW cosines
// (gx,gy) via 64-lane butterfly + alongH partials (gx,gz) in regs. Odd blocks:
// role B (d-walk): alongD partials (gy,gz) in regs. Main loops sync-free;
// one __syncthreads in the tail. 40 active float4-lanes per wave cover W=160.
// ---------------------------------------------------------------------------
__global__ __launch_bounds__(NTHR, 4) void mainAB(const float* __restrict__ f,
                                                  const float* __restrict__ t,
                                                  float* __restrict__ P,
                                                  float* __restrict__ out) {
  __shared__ float sd[NWAVE * 40 * 25];   // padded stride 25: conflict-free
  __shared__ float cpad[NWAVE];
  const int tid = threadIdx.x;
  const int wv = tid >> 6;
  const int l = tid & 63;
  const bool act = (l < 40);
  const int w = act ? 4 * l : 156;
  const int wn = (w + 4 < WW) ? (w + 4) : (WW - 1);  // clamp -> gz[3]=0 at w=159
  const int blk = blockIdx.x;
  const bool roleA = ((blk & 1) == 0);
  const int id = blk >> 1;

  float acc[24];                 // alongH (A: gx,gz) or alongD (B: gy,gz) partials
#pragma unroll
  for (int c = 0; c < 24; ++c) acc[c] = 0.0f;

  int vbase1, vbase2, ch;
  float accCos = 0.0f;

  if (roleA) {
    const int hc = id % NC;
    const int bd = id / NC;
    const int d = bd % DD;
    const size_t base = (size_t)bd * SLICE;
    const float* fp = f + base;
    const float* tp = t + base;
    const int dstep = (d < DD - 1) ? SLICE : 0;     // clamp -> gx = 0
    const int h0 = hc * RPC + wv * RPW;
    vbase1 = bd * 160;            // gx alongH
    vbase2 = NV + bd * 160;       // gz alongH
    ch = hc;

    float4 F0, T0;
    if (act) {
      F0 = *(const float4*)(fp + h0 * WW + w);
      T0 = *(const float4*)(tp + h0 * WW + w);
    }
#pragma unroll
    for (int it = 0; it < RPW; ++it) {
      const int h = h0 + it;
      const int hstep = (h < HH - 1) ? WW : 0;      // clamp -> gy = 0
      const float* rf = fp + h * WW;
      const float* rt = tp + h * WW;
      float xd = 0, xf = 0, xt = 0, yd = 0, yf = 0, yt = 0;
      if (act) {
        const float4 FD = *(const float4*)(rf + dstep + w);
        const float4 TD = *(const float4*)(rt + dstep + w);
        const float4 F1 = *(const float4*)(rf + hstep + w);   // row h+1 self
        const float4 T1 = *(const float4*)(rt + hstep + w);
        const float fz = rf[wn], tz = rt[wn];
#pragma unroll
        for (int j = 0; j < 4; ++j) {
          const float f0 = ELEM(F0, j), t0 = ELEM(T0, j);
          const float gxf = ELEM(FD, j) - f0, gxt = ELEM(TD, j) - t0;
          const float gyf = ELEM(F1, j) - f0, gyt = ELEM(T1, j) - t0;
          const float fnx = (j < 3) ? ELEM(F0, j + 1) : fz;
          const float tnx = (j < 3) ? ELEM(T0, j + 1) : tz;
          const float gzf = fnx - f0, gzt = tnx - t0;
          xd += gxf * gxt; xf += gxf * gxf; xt += gxt * gxt;
          yd += gyf * gyt; yf += gyf * gyf; yt += gyt * gyt;
          acc[j * 6 + 0] += gxf * gxt; acc[j * 6 + 1] += gxf * gxf; acc[j * 6 + 2] += gxt * gxt;
          acc[j * 6 + 3] += gzf * gzt; acc[j * 6 + 4] += gzf * gzf; acc[j * 6 + 5] += gzt * gzt;
        }
        F0 = F1; T0 = T1;        // register reuse: next row's self
      }
      // convergent 64-lane butterfly (inactive lanes contribute zeros)
#pragma unroll
      for (int m = 1; m <= 32; m <<= 1) {
        xd += __shfl_xor(xd, m); xf += __shfl_xor(xf, m); xt += __shfl_xor(xt, m);
        yd += __shfl_xor(yd, m); yf += __shfl_xor(yf, m); yt += __shfl_xor(yt, m);
      }
      if (l == 0) {
        accCos += xd / (fmaxf(sqrtf(xf), EPS) * fmaxf(sqrtf(xt), EPS));
        accCos += yd / (fmaxf(sqrtf(yf), EPS) * fmaxf(sqrtf(yt), EPS));
      }
    }
  } else {
    // ---------------- role B (d-walk) ----------------
    const int dc = id % NC;
    const int bh = id / NC;
    const int b = bh / HH;
    const int h = bh % HH;
    const float* fp = f + (size_t)b * DD * SLICE + (size_t)h * WW;
    const float* tp = t + (size_t)b * DD * SLICE + (size_t)h * WW;
    const int hstep = (h < HH - 1) ? WW : 0;        // clamp -> gy = 0
    const int d0 = dc * RPC + wv * RPW;
    vbase1 = 2 * NV + bh * 160;   // gy alongD
    vbase2 = 3 * NV + bh * 160;   // gz alongD
    ch = dc;

#pragma unroll
    for (int it = 0; it < RPW; ++it) {
      const float* rf = fp + (size_t)(d0 + it) * SLICE;
      const float* rt = tp + (size_t)(d0 + it) * SLICE;
      if (act) {
        const float4 F0 = *(const float4*)(rf + w);
        const float4 T0 = *(const float4*)(rt + w);
        const float4 FH = *(const float4*)(rf + hstep + w);
        const float4 TH = *(const float4*)(rt + hstep + w);
        const float fz = rf[wn], tz = rt[wn];
#pragma unroll
        for (int j = 0; j < 4; ++j) {
          const float f0 = ELEM(F0, j), t0 = ELEM(T0, j);
          const float gyf = ELEM(FH, j) - f0, gyt = ELEM(TH, j) - t0;
          const float fnx = (j < 3) ? ELEM(F0, j + 1) : fz;
          const float tnx = (j < 3) ? ELEM(T0, j + 1) : tz;
          const float gzf = fnx - f0, gzt = tnx - t0;
          acc[j * 6 + 0] += gyf * gyt; acc[j * 6 + 1] += gyf * gyf; acc[j * 6 + 2] += gyt * gyt;
          acc[j * 6 + 3] += gzf * gzt; acc[j * 6 + 4] += gzf * gzf; acc[j * 6 + 5] += gzt * gzt;
        }
      }
    }
  }

  // ---------------- common tail: cross-wave combine + P writes ----------------
  if (act) {
    float* s = &sd[(wv * 40 + l) * 25];
#pragma unroll
    for (int c = 0; c < 24; ++c) s[c] = acc[c];
  }
  if (roleA && l == 0) cpad[wv] = accCos;
  __syncthreads();
  if (roleA && tid == 0)
    atomicAdd(out, (cpad[0] + cpad[1] + cpad[2] + cpad[3]) * SCALE);

  if (tid < 160) {
    const int ll = tid >> 2, j = tid & 3;   // w-position wi = tid
    float s[6];
#pragma unroll
    for (int c = 0; c < 6; ++c) {
      s[c] = sd[(0 * 40 + ll) * 25 + j * 6 + c] + sd[(1 * 40 + ll) * 25 + j * 6 + c]
           + sd[(2 * 40 + ll) * 25 + j * 6 + c] + sd[(3 * 40 + ll) * 25 + j * 6 + c];
    }
    const size_t o1 = ((size_t)ch * NVTOT + (vbase1 + tid)) * 3;
    const size_t o2 = ((size_t)ch * NVTOT + (vbase2 + tid)) * 3;
    P[o1 + 0] = s[0]; P[o1 + 1] = s[1]; P[o1 + 2] = s[2];
    P[o2 + 0] = s[3]; P[o2 + 1] = s[4]; P[o2 + 2] = s[5];
  }
}

// ---------------------------------------------------------------------------
// Combine chunk partials -> cosines -> loss.
// ---------------------------------------------------------------------------
__global__ __launch_bounds__(256) void finalize_kernel(const float* __restrict__ P,
                                                       float* __restrict__ out) {
  const int v = blockIdx.x * 256 + threadIdx.x;
  float c = 0.0f;
  if (v < NVTOT) {
    float dot = 0.0f, ff = 0.0f, tt = 0.0f;
#pragma unroll
    for (int ch = 0; ch < NC; ++ch) {
      const size_t o = ((size_t)ch * NVTOT + v) * 3;
      dot += P[o]; ff += P[o + 1]; tt += P[o + 2];
    }
    c = dot / (fmaxf(sqrtf(ff), EPS) * fmaxf(sqrtf(tt), EPS));
  }
#pragma unroll
  for (int m = 32; m >= 1; m >>= 1) c += __shfl_xor(c, m);
  __shared__ float part[4];
  if ((threadIdx.x & 63) == 0) part[threadIdx.x >> 6] = c;
  __syncthreads();
  if (threadIdx.x == 0) atomicAdd(out, (part[0] + part[1] + part[2] + part[3]) * SCALE);
}

extern "C" void kernel_launch(void* const* d_in, const int* in_sizes, int n_in,
                              void* d_out, int out_size, void* d_ws, size_t ws_size,
                              hipStream_t stream) {
  const float* fk = (const float*)d_in[0];
  const float* tr = (const float*)d_in[1];
  float* out = (float*)d_out;
  float* P = (float*)d_ws;   // NC*NVTOT*3 floats = 12.3 MB

  hipLaunchKernelGGL(zero_kernel, dim3(1), dim3(64), 0, stream, out);
  hipLaunchKernelGGL(mainAB, dim3(2 * NB * DD * NC), dim3(NTHR), 0, stream, fk, tr, P, out);
  hipLaunchKernelGGL(finalize_kernel, dim3((NVTOT + 255) / 256), dim3(256), 0, stream, P, out);
}